// Round 14
// baseline (168.367 us; speedup 1.0000x reference)
//
#include <hip/hip_runtime.h>
#include <hip/hip_bf16.h>

namespace {

constexpr int T = 4, H = 128, W = 128, C = 256, HD = 8, K = 9, F = 32;
constexpr int M = T * H * W;  // 65536

typedef __attribute__((ext_vector_type(8))) short short8v;   // 8 bf16 (4 VGPR)
typedef __attribute__((ext_vector_type(4))) float f32x4;     // MFMA acc

__device__ __forceinline__ unsigned short f2bf(float f) {
  unsigned u = __float_as_uint(f);
  unsigned r = (u + 0x7fffu + ((u >> 16) & 1u)) >> 16;
  return (unsigned short)r;
}

__device__ __forceinline__ float bf2f(unsigned short u) {
  return __uint_as_float(((unsigned)u) << 16);
}

// ---------------------------------------------------------------------------
// Templated MFMA GEMM (unchanged, counter-proven near memory floor)
// ALAYOUT: 0 = fp32 row-major [M][256]; 2 = bf16 head-major [head][M][32]
// ---------------------------------------------------------------------------
template <int ALAYOUT, bool OUT_F32>
__global__ __launch_bounds__(256) void mfma_gemm(
    const void* __restrict__ Aptr, const float* __restrict__ Bw,
    void* __restrict__ Cptr, const float* __restrict__ bias) {
  __shared__ unsigned short As[128][40];
  __shared__ unsigned short Bs[128][40];
  const int m0 = blockIdx.x * 128;
  const int n0 = blockIdx.y * 128;
  const int t = threadIdx.x;
  const int lane = t & 63;
  const int wid = t >> 6;
  const int wm = wid >> 1, wn = wid & 1;
  const int fr = lane & 15;
  const int kg = lane >> 4;

  f32x4 acc[4][4];
#pragma unroll
  for (int ni = 0; ni < 4; ++ni) {
    float b = 0.f;
    if (OUT_F32) b = bias[n0 + wn * 64 + ni * 16 + fr];
#pragma unroll
    for (int mi = 0; mi < 4; ++mi) {
      acc[mi][ni][0] = b; acc[mi][ni][1] = b;
      acc[mi][ni][2] = b; acc[mi][ni][3] = b;
    }
  }

  for (int k0 = 0; k0 < C; k0 += 32) {
    __syncthreads();
    if (ALAYOUT == 2) {
      const unsigned short* Ab = (const unsigned short*)Aptr;
      const size_t hb = (size_t)(k0 >> 5) * M * 32;
#pragma unroll
      for (int i = 0; i < 2; ++i) {
        const int flat = t + i * 256;          // 0..511
        const int row = flat >> 2, kc = (flat & 3) * 8;
        *(short8v*)&As[row][kc] =
            *(const short8v*)(Ab + hb + (size_t)(m0 + row) * 32 + kc);
      }
    } else {
      const float* Af = (const float*)Aptr;
#pragma unroll
      for (int i = 0; i < 4; ++i) {
        const int flat = t + i * 256;          // 0..1023
        const int row = flat >> 3, kc = (flat & 7) * 4;
        const float4 v4 = *(const float4*)(Af + (size_t)(m0 + row) * C + k0 + kc);
        ushort4 o;
        o.x = f2bf(v4.x); o.y = f2bf(v4.y); o.z = f2bf(v4.z); o.w = f2bf(v4.w);
        *(ushort4*)&As[row][kc] = o;
      }
    }
#pragma unroll
    for (int i = 0; i < 4; ++i) {
      const int flat = t + i * 256;
      const int row = flat >> 3, kc = (flat & 7) * 4;
      const float4 v4 = *(const float4*)(Bw + (size_t)(n0 + row) * C + k0 + kc);
      ushort4 o;
      o.x = f2bf(v4.x); o.y = f2bf(v4.y); o.z = f2bf(v4.z); o.w = f2bf(v4.w);
      *(ushort4*)&Bs[row][kc] = o;
    }
    __syncthreads();
    short8v af[4], bfv[4];
#pragma unroll
    for (int mi = 0; mi < 4; ++mi)
      af[mi] = *(const short8v*)&As[wm * 64 + mi * 16 + fr][kg * 8];
#pragma unroll
    for (int ni = 0; ni < 4; ++ni)
      bfv[ni] = *(const short8v*)&Bs[wn * 64 + ni * 16 + fr][kg * 8];
#pragma unroll
    for (int mi = 0; mi < 4; ++mi)
#pragma unroll
      for (int ni = 0; ni < 4; ++ni)
        acc[mi][ni] = __builtin_amdgcn_mfma_f32_16x16x32_bf16(
            af[mi], bfv[ni], acc[mi][ni], 0, 0, 0);
  }

#pragma unroll
  for (int mi = 0; mi < 4; ++mi) {
#pragma unroll
    for (int ni = 0; ni < 4; ++ni) {
      const int gcol = n0 + wn * 64 + ni * 16 + fr;
#pragma unroll
      for (int r = 0; r < 4; ++r) {
        const int grow = m0 + wm * 64 + mi * 16 + kg * 4 + r;
        if (OUT_F32) {
          ((float*)Cptr)[(size_t)grow * C + gcol] = acc[mi][ni][r];
        } else {
          ((unsigned short*)Cptr)[(size_t)grow * C + gcol] = f2bf(acc[mi][ni][r]);
        }
      }
    }
  }
}

// ---------------------------------------------------------------------------
// Gather v13: 256-thread blocks (the only shape with proven ~88-VGPR
// allocation — r7/r9/r13 all spilled at 512), 4h x 8w tile, all 4 t, one
// head. Halo 4 x 10 x 14 slivers x 64B = 35840B -> 4 blocks/CU (16 waves,
// was 12 at 50KB).
//   waves 0-1 (tid<128): compute — one output/thread, full 32f, identical
//     r12 math: metadata load + decode overlap the stagers' DMA; barrier;
//     LDS weighted-sum; store.
//   waves 2-3 (tid>=128): stagers — 2240 x 16B pieces in 2 batched epochs
//     (9 + 8.5/thread), rotation swizzle, then barrier + retire.
// ---------------------------------------------------------------------------
struct __attribute__((packed, aligned(4))) I4p { int a, b, c, d; };
struct __attribute__((packed, aligned(4))) I2p { int a, b; };
struct __attribute__((packed, aligned(4))) F4p { float a, b, c, d; };

__global__ __launch_bounds__(256, 4) void gather_lds_kernel(
    const unsigned short* __restrict__ v, const float* __restrict__ attn,
    const int* __restrict__ flows, unsigned short* __restrict__ agg2) {
  __shared__ __align__(16) unsigned short halo[560 * 32];  // 35840 B
  // bijective XCD-chunk swizzle: 4096 blocks = 8 XCDs x 512; head fastest.
  const int nb = (blockIdx.x & 7) * 512 + (blockIdx.x >> 3);
  const int head = nb & 7;
  const int tile = nb >> 3;          // 0..511 over 32x16 grid of 4x8 tiles
  const int h0 = (tile >> 4) * 4;
  const int w0 = (tile & 15) * 8;
  const int tid = threadIdx.x;
  const unsigned short* vhead = v + head * F;

  if (tid >= 128) {
    // ---------------- stager waves (2) ----------------
    const int stid = tid - 128;  // 0..127
    auto piece_src = [&](int pi, int& ldsoff) -> const short8v* {
      const int sliver = pi >> 2, j = pi & 3;
      const int tt = sliver / 140;
      const int rem = sliver - tt * 140;
      const int hh = rem / 14;
      const int ww = rem - hh * 14;
      const int hc = min(max(h0 - 3 + hh, 0), H - 1);
      const int wc = min(max(w0 - 3 + ww, 0), W - 1);
      const int sm = (tt << 14) | (hc << 7) | wc;
      const int jj = (j + (sliver >> 1)) & 3;  // rotation swizzle
      ldsoff = sliver * 32 + jj * 8;
      return (const short8v*)(vhead + (size_t)sm * C + j * 8);
    };
    {  // epoch A: pieces 0..1151 (9 per thread)
      short8v pc[9]; int lo[9];
#pragma unroll
      for (int e = 0; e < 9; ++e) pc[e] = *piece_src(stid + e * 128, lo[e]);
#pragma unroll
      for (int e = 0; e < 9; ++e) *(short8v*)&halo[lo[e]] = pc[e];
    }
    {  // epoch B: pieces 1152..2239 (8 per thread + 64-thread tail)
      short8v pc[8]; int lo[8];
#pragma unroll
      for (int e = 0; e < 8; ++e)
        pc[e] = *piece_src(1152 + stid + e * 128, lo[e]);
      short8v pt; int lot = 0;
      if (stid < 64) pt = *piece_src(2176 + stid, lot);
#pragma unroll
      for (int e = 0; e < 8; ++e) *(short8v*)&halo[lo[e]] = pc[e];
      if (stid < 64) *(short8v*)&halo[lot] = pt;
    }
    __syncthreads();
    return;
  }

  // ---------------- compute waves (2) ----------------
  const int s = tid & 31;            // spatial 0..31 (4h x 8w)
  const int tq = tid >> 5;           // output t-plane 0..3
  const int h = h0 + (s >> 3);
  const int w = w0 + (s & 7);
  const int m = (tq << 14) | (h << 7) | w;

  const int base = ((head << 16) | m) * K;
  const int fb = base * 3;
  const I4p f0 = *(const I4p*)(flows + fb + 0);
  const I4p f1 = *(const I4p*)(flows + fb + 4);
  const I4p f2 = *(const I4p*)(flows + fb + 8);
  const I4p f3 = *(const I4p*)(flows + fb + 12);
  const I4p f4 = *(const I4p*)(flows + fb + 16);
  const I4p f5 = *(const I4p*)(flows + fb + 20);
  const I2p f6 = *(const I2p*)(flows + fb + 24);
  const int f7 = flows[fb + 26];
  const F4p a0 = *(const F4p*)(attn + base + 0);
  const F4p a1 = *(const F4p*)(attn + base + 4);
  const float a2 = attn[base + 8];

  const int d[27] = {f0.a, f0.b, f0.c, f0.d, f1.a, f1.b, f1.c, f1.d,
                     f2.a, f2.b, f2.c, f2.d, f3.a, f3.b, f3.c, f3.d,
                     f4.a, f4.b, f4.c, f4.d, f5.a, f5.b, f5.c, f5.d,
                     f6.a, f6.b, f7};
  const float aw[9] = {a0.a, a0.b, a0.c, a0.d, a1.a, a1.b, a1.c, a1.d, a2};
  int row[9];
#pragma unroll
  for (int k = 0; k < 9; ++k) {
    const int ts = min(max(tq + d[3 * k + 0], 0), T - 1);
    const int hs = min(max(h + d[3 * k + 1], 0), H - 1) - (h0 - 3);
    const int ws = min(max(w + d[3 * k + 2], 0), W - 1) - (w0 - 3);
    row[k] = (ts * 10 + hs) * 14 + ws;
  }

  __syncthreads();

  float acc[32];
#pragma unroll
  for (int i = 0; i < 32; ++i) acc[i] = 0.f;
#pragma unroll
  for (int k = 0; k < 9; ++k) {
    const int rbase = row[k] * 32;
    const int rot = (row[k] >> 1) & 3;
#pragma unroll
    for (int j = 0; j < 4; ++j) {
      const short8v p = *(const short8v*)&halo[rbase + (((j + rot) & 3)) * 8];
#pragma unroll
      for (int e = 0; e < 8; ++e)
        acc[j * 8 + e] += aw[k] * bf2f((unsigned short)p[e]);
    }
  }

  unsigned short* dst = agg2 + ((size_t)head * M + m) * F;
#pragma unroll
  for (int j = 0; j < 4; ++j) {
    short8v o;
#pragma unroll
    for (int e = 0; e < 8; ++e) o[e] = (short)f2bf(acc[j * 8 + e]);
    *(short8v*)(dst + j * 8) = o;
  }
}

// ---------------------------------------------------------------------------
// Fallback (ws too small): fused gather + fp32 proj GEMM. Proven.
// ---------------------------------------------------------------------------
__global__ __launch_bounds__(256) void agg_proj_kernel(
    const unsigned short* __restrict__ v, const float* __restrict__ attn,
    const int* __restrict__ flows, const float* __restrict__ proj_w,
    const float* __restrict__ proj_b, float* __restrict__ out) {
  __shared__ float Agg[32][C];
  __shared__ float Bs[32][C];
  const int bid = blockIdx.x;
  const int t = bid >> 9;
  const int h0 = ((bid >> 5) & 15) * 8;
  const int w0 = (bid & 31) * 4;
  const int tid = threadIdx.x;

  const int g = tid >> 3;
  const int f4 = (tid & 7) * 4;
#pragma unroll
  for (int r = 0; r < 8; ++r) {
    const int pi = r * 32 + g;
    const int pos = pi >> 3;
    const int head = pi & 7;
    const int h = h0 + (pos >> 2);
    const int w = w0 + (pos & 3);
    const int base = (((head * T + t) * H + h) * W + w) * K;
    const int fbase = base * 3;
    float4 acc = {0.f, 0.f, 0.f, 0.f};
#pragma unroll
    for (int k = 0; k < K; ++k) {
      const int dt = flows[fbase + k * 3 + 0];
      const int dh = flows[fbase + k * 3 + 1];
      const int dw = flows[fbase + k * 3 + 2];
      const float aw = attn[base + k];
      const int tt = min(max(t + dt, 0), T - 1);
      const int hh = min(max(h + dh, 0), H - 1);
      const int ww = min(max(w + dw, 0), W - 1);
      const int mm = (tt * H + hh) * W + ww;
      const ushort4 r4 = *(const ushort4*)(v + (size_t)mm * C + head * F + f4);
      acc.x += aw * bf2f(r4.x);
      acc.y += aw * bf2f(r4.y);
      acc.z += aw * bf2f(r4.z);
      acc.w += aw * bf2f(r4.w);
    }
    *(float4*)&Agg[pos][head * F + f4] = acc;
  }
  __syncthreads();

  const int tx = tid & 31;
  const int ty = tid >> 5;
  float acc2[4][8];
  {
    const float4 b0 = *(const float4*)(proj_b + tx * 8);
    const float4 b1 = *(const float4*)(proj_b + tx * 8 + 4);
#pragma unroll
    for (int i = 0; i < 4; ++i) {
      acc2[i][0] = b0.x; acc2[i][1] = b0.y; acc2[i][2] = b0.z; acc2[i][3] = b0.w;
      acc2[i][4] = b1.x; acc2[i][5] = b1.y; acc2[i][6] = b1.z; acc2[i][7] = b1.w;
    }
  }
  for (int k0 = 0; k0 < C; k0 += 32) {
#pragma unroll
    for (int i = 0; i < 8; ++i) {
      const float4 w4 = *(const float4*)(proj_w + (size_t)tid * C + k0 + i * 4);
      Bs[i * 4 + 0][tid] = w4.x;
      Bs[i * 4 + 1][tid] = w4.y;
      Bs[i * 4 + 2][tid] = w4.z;
      Bs[i * 4 + 3][tid] = w4.w;
    }
    __syncthreads();
#pragma unroll 4
    for (int kk = 0; kk < 32; ++kk) {
      const float4 bb0 = *(const float4*)&Bs[kk][tx * 8];
      const float4 bb1 = *(const float4*)&Bs[kk][tx * 8 + 4];
      float a[4];
#pragma unroll
      for (int i = 0; i < 4; ++i) a[i] = Agg[ty * 4 + i][k0 + kk];
#pragma unroll
      for (int i = 0; i < 4; ++i) {
        acc2[i][0] += a[i] * bb0.x;
        acc2[i][1] += a[i] * bb0.y;
        acc2[i][2] += a[i] * bb0.z;
        acc2[i][3] += a[i] * bb0.w;
        acc2[i][4] += a[i] * bb1.x;
        acc2[i][5] += a[i] * bb1.y;
        acc2[i][6] += a[i] * bb1.z;
        acc2[i][7] += a[i] * bb1.w;
      }
    }
    __syncthreads();
  }
#pragma unroll
  for (int i = 0; i < 4; ++i) {
    const int pos = ty * 4 + i;
    const int h = h0 + (pos >> 2);
    const int w = w0 + (pos & 3);
    const int m = (t * H + h) * W + w;
    float4 o0, o1;
    o0.x = acc2[i][0]; o0.y = acc2[i][1]; o0.z = acc2[i][2]; o0.w = acc2[i][3];
    o1.x = acc2[i][4]; o1.y = acc2[i][5]; o1.z = acc2[i][6]; o1.w = acc2[i][7];
    *(float4*)(out + (size_t)m * C + tx * 8) = o0;
    *(float4*)(out + (size_t)m * C + tx * 8 + 4) = o1;
  }
}

}  // namespace

extern "C" void kernel_launch(void* const* d_in, const int* in_sizes, int n_in,
                              void* d_out, int out_size, void* d_ws,
                              size_t ws_size, hipStream_t stream) {
  const float* x = (const float*)d_in[0];
  const float* attn = (const float*)d_in[1];
  const int* flows = (const int*)d_in[2];
  const float* v_w = (const float*)d_in[3];
  const float* proj_w = (const float*)d_in[4];
  const float* proj_b = (const float*)d_in[5];
  float* out = (float*)d_out;

  const size_t VBYTES = (size_t)M * C * 2;  // 32 MB bf16
  unsigned short* v = (unsigned short*)d_ws;

  dim3 g1(M / 128, C / 128);
  mfma_gemm<0, false><<<g1, 256, 0, stream>>>(x, v_w, v, nullptr);

  if (ws_size >= 2 * VBYTES) {
    unsigned short* agg2 = (unsigned short*)((char*)d_ws + VBYTES);
    gather_lds_kernel<<<4096, 256, 0, stream>>>(v, attn, flows, agg2);
    mfma_gemm<2, true><<<g1, 256, 0, stream>>>(agg2, proj_w, out, proj_b);
  } else {
    const int nblk = T * (H / 8) * (W / 4);  // 2048
    agg_proj_kernel<<<nblk, 256, 0, stream>>>(v, attn, flows, proj_w, proj_b,
                                              out);
  }
}

// Round 15
// 97.656 us; speedup vs baseline: 1.7241x; 1.7241x over previous
//
#include <hip/hip_runtime.h>
#include <hip/hip_bf16.h>

namespace {

constexpr int T = 4, H = 128, W = 128, C = 256, HD = 8, K = 9, F = 32;
constexpr int M = T * H * W;  // 65536

typedef __attribute__((ext_vector_type(8))) short short8v;   // 8 bf16 (4 VGPR)
typedef __attribute__((ext_vector_type(4))) float f32x4;     // MFMA acc

__device__ __forceinline__ unsigned short f2bf(float f) {
  unsigned u = __float_as_uint(f);
  unsigned r = (u + 0x7fffu + ((u >> 16) & 1u)) >> 16;
  return (unsigned short)r;
}

__device__ __forceinline__ float bf2f(unsigned short u) {
  return __uint_as_float(((unsigned)u) << 16);
}

// ---------------------------------------------------------------------------
// Templated MFMA GEMM (unchanged, counter-proven near memory floor)
// ALAYOUT: 0 = fp32 row-major [M][256]; 2 = bf16 head-major [head][M][32]
// ---------------------------------------------------------------------------
template <int ALAYOUT, bool OUT_F32>
__global__ __launch_bounds__(256) void mfma_gemm(
    const void* __restrict__ Aptr, const float* __restrict__ Bw,
    void* __restrict__ Cptr, const float* __restrict__ bias) {
  __shared__ unsigned short As[128][40];
  __shared__ unsigned short Bs[128][40];
  const int m0 = blockIdx.x * 128;
  const int n0 = blockIdx.y * 128;
  const int t = threadIdx.x;
  const int lane = t & 63;
  const int wid = t >> 6;
  const int wm = wid >> 1, wn = wid & 1;
  const int fr = lane & 15;
  const int kg = lane >> 4;

  f32x4 acc[4][4];
#pragma unroll
  for (int ni = 0; ni < 4; ++ni) {
    float b = 0.f;
    if (OUT_F32) b = bias[n0 + wn * 64 + ni * 16 + fr];
#pragma unroll
    for (int mi = 0; mi < 4; ++mi) {
      acc[mi][ni][0] = b; acc[mi][ni][1] = b;
      acc[mi][ni][2] = b; acc[mi][ni][3] = b;
    }
  }

  for (int k0 = 0; k0 < C; k0 += 32) {
    __syncthreads();
    if (ALAYOUT == 2) {
      const unsigned short* Ab = (const unsigned short*)Aptr;
      const size_t hb = (size_t)(k0 >> 5) * M * 32;
#pragma unroll
      for (int i = 0; i < 2; ++i) {
        const int flat = t + i * 256;          // 0..511
        const int row = flat >> 2, kc = (flat & 3) * 8;
        *(short8v*)&As[row][kc] =
            *(const short8v*)(Ab + hb + (size_t)(m0 + row) * 32 + kc);
      }
    } else {
      const float* Af = (const float*)Aptr;
#pragma unroll
      for (int i = 0; i < 4; ++i) {
        const int flat = t + i * 256;          // 0..1023
        const int row = flat >> 3, kc = (flat & 7) * 4;
        const float4 v4 = *(const float4*)(Af + (size_t)(m0 + row) * C + k0 + kc);
        ushort4 o;
        o.x = f2bf(v4.x); o.y = f2bf(v4.y); o.z = f2bf(v4.z); o.w = f2bf(v4.w);
        *(ushort4*)&As[row][kc] = o;
      }
    }
#pragma unroll
    for (int i = 0; i < 4; ++i) {
      const int flat = t + i * 256;
      const int row = flat >> 3, kc = (flat & 7) * 4;
      const float4 v4 = *(const float4*)(Bw + (size_t)(n0 + row) * C + k0 + kc);
      ushort4 o;
      o.x = f2bf(v4.x); o.y = f2bf(v4.y); o.z = f2bf(v4.z); o.w = f2bf(v4.w);
      *(ushort4*)&Bs[row][kc] = o;
    }
    __syncthreads();
    short8v af[4], bfv[4];
#pragma unroll
    for (int mi = 0; mi < 4; ++mi)
      af[mi] = *(const short8v*)&As[wm * 64 + mi * 16 + fr][kg * 8];
#pragma unroll
    for (int ni = 0; ni < 4; ++ni)
      bfv[ni] = *(const short8v*)&Bs[wn * 64 + ni * 16 + fr][kg * 8];
#pragma unroll
    for (int mi = 0; mi < 4; ++mi)
#pragma unroll
      for (int ni = 0; ni < 4; ++ni)
        acc[mi][ni] = __builtin_amdgcn_mfma_f32_16x16x32_bf16(
            af[mi], bfv[ni], acc[mi][ni], 0, 0, 0);
  }

#pragma unroll
  for (int mi = 0; mi < 4; ++mi) {
#pragma unroll
    for (int ni = 0; ni < 4; ++ni) {
      const int gcol = n0 + wn * 64 + ni * 16 + fr;
#pragma unroll
      for (int r = 0; r < 4; ++r) {
        const int grow = m0 + wm * 64 + mi * 16 + kg * 4 + r;
        if (OUT_F32) {
          ((float*)Cptr)[(size_t)grow * C + gcol] = acc[mi][ni][r];
        } else {
          ((unsigned short*)Cptr)[(size_t)grow * C + gcol] = f2bf(acc[mi][ni][r]);
        }
      }
    }
  }
}

// ---------------------------------------------------------------------------
// Gather v14: r12's UNIFORM-role structure (the only shape that doesn't
// spill: every thread stages AND computes; no divergent role branch), with:
//  - 8h x 4w tile (halo 4 x 14 x 10 slivers x 64B = 35840B) -> 4 blocks/CU,
//    16-wave/CU ceiling (r12: 12).
//  - thread = (output, f-half): fh = tid&1. Lane pairs 2o/2o+1 load the SAME
//    metadata lines (coalesced within the wave — unlike r7's cross-wave
//    split which doubled FETCH). Per-thread chains halve: 18 LDS reads,
//    144 FMA, 32B store.
//  - single 9-piece batched staging epoch (2240 pieces), rotation swizzle.
//  - 4096 blocks, bijective XCD chunking, head fastest.
// ---------------------------------------------------------------------------
struct __attribute__((packed, aligned(4))) I4p { int a, b, c, d; };
struct __attribute__((packed, aligned(4))) I2p { int a, b; };
struct __attribute__((packed, aligned(4))) F4p { float a, b, c, d; };

__global__ __launch_bounds__(256, 4) void gather_lds_kernel(
    const unsigned short* __restrict__ v, const float* __restrict__ attn,
    const int* __restrict__ flows, unsigned short* __restrict__ agg2) {
  __shared__ __align__(16) unsigned short halo[560 * 32];  // 35840 B
  // bijective XCD-chunk swizzle: 4096 = 8 XCDs x 512; head fastest.
  const int nb = (blockIdx.x & 7) * 512 + (blockIdx.x >> 3);
  const int head = nb & 7;
  const int tile = nb >> 3;          // 0..511 over 16x32 grid of 8x4 tiles
  const int h0 = (tile >> 5) * 8;
  const int w0 = (tile & 31) * 4;
  const int tid = threadIdx.x;
  const int o = tid >> 1;            // output 0..127
  const int fh = tid & 1;            // f-half (16 bf16 = 32B)
  const int tq = o >> 5;             // t-plane 0..3
  const int s = o & 31;              // spatial 0..31 (8h x 4w)
  const int h = h0 + (s >> 2);
  const int w = w0 + (s & 3);
  const int m = (tq << 14) | (h << 7) | w;
  const unsigned short* vhead = v + head * F;

  // ---- metadata loads (lane pairs hit same lines -> coalesced) ----
  const int base = ((head << 16) | m) * K;
  const int fb = base * 3;
  const I4p f0 = *(const I4p*)(flows + fb + 0);
  const I4p f1 = *(const I4p*)(flows + fb + 4);
  const I4p f2 = *(const I4p*)(flows + fb + 8);
  const I4p f3 = *(const I4p*)(flows + fb + 12);
  const I4p f4 = *(const I4p*)(flows + fb + 16);
  const I4p f5 = *(const I4p*)(flows + fb + 20);
  const I2p f6 = *(const I2p*)(flows + fb + 24);
  const int f7 = flows[fb + 26];
  const F4p a0 = *(const F4p*)(attn + base + 0);
  const F4p a1 = *(const F4p*)(attn + base + 4);
  const float a2 = attn[base + 8];

  // ---- stage halo: 2240 x 16B pieces, ONE batched epoch ----
  auto piece_src = [&](int pi, int& ldsoff) -> const short8v* {
    const int sliver = pi >> 2, j = pi & 3;
    const int tt = sliver / 140;
    const int rem = sliver - tt * 140;
    const int hh = rem / 10;
    const int ww = rem - hh * 10;
    const int hc = min(max(h0 - 3 + hh, 0), H - 1);
    const int wc = min(max(w0 - 3 + ww, 0), W - 1);
    const int sm = (tt << 14) | (hc << 7) | wc;
    const int jj = (j + (sliver >> 1)) & 3;  // rotation swizzle (bank-uniform)
    ldsoff = sliver * 32 + jj * 8;
    return (const short8v*)(vhead + (size_t)sm * C + j * 8);
  };
  {
    short8v pc[8]; int lo[8];
#pragma unroll
    for (int e = 0; e < 8; ++e) pc[e] = *piece_src(tid + e * 256, lo[e]);
    short8v pt; int lot = 0;
    if (tid < 192) pt = *piece_src(2048 + tid, lot);  // tail 2048..2239
#pragma unroll
    for (int e = 0; e < 8; ++e) *(short8v*)&halo[lo[e]] = pc[e];
    if (tid < 192) *(short8v*)&halo[lot] = pt;
  }

  // ---- decode offsets -> halo rows ----
  const int d[27] = {f0.a, f0.b, f0.c, f0.d, f1.a, f1.b, f1.c, f1.d,
                     f2.a, f2.b, f2.c, f2.d, f3.a, f3.b, f3.c, f3.d,
                     f4.a, f4.b, f4.c, f4.d, f5.a, f5.b, f5.c, f5.d,
                     f6.a, f6.b, f7};
  const float aw[9] = {a0.a, a0.b, a0.c, a0.d, a1.a, a1.b, a1.c, a1.d, a2};
  int row[9];
#pragma unroll
  for (int k = 0; k < 9; ++k) {
    const int ts = min(max(tq + d[3 * k + 0], 0), T - 1);
    const int hs = min(max(h + d[3 * k + 1], 0), H - 1) - (h0 - 3);
    const int ws = min(max(w + d[3 * k + 2], 0), W - 1) - (w0 - 3);
    row[k] = (ts * 14 + hs) * 10 + ws;
  }

  __syncthreads();

  // ---- weighted sum from LDS (this thread's 16-elem f-half) ----
  float acc[16];
#pragma unroll
  for (int i = 0; i < 16; ++i) acc[i] = 0.f;
#pragma unroll
  for (int k = 0; k < 9; ++k) {
    const int rbase = row[k] * 32;
    const int rot = (row[k] >> 1) & 3;
#pragma unroll
    for (int jl = 0; jl < 2; ++jl) {
      const int j = fh * 2 + jl;
      const short8v p = *(const short8v*)&halo[rbase + (((j + rot) & 3)) * 8];
#pragma unroll
      for (int e = 0; e < 8; ++e)
        acc[jl * 8 + e] += aw[k] * bf2f((unsigned short)p[e]);
    }
  }

  // ---- store head-major: agg2[head][M][32]; lane pair covers 64B ----
  unsigned short* dst = agg2 + ((size_t)head * M + m) * F + fh * 16;
#pragma unroll
  for (int jl = 0; jl < 2; ++jl) {
    short8v ov;
#pragma unroll
    for (int e = 0; e < 8; ++e) ov[e] = (short)f2bf(acc[jl * 8 + e]);
    *(short8v*)(dst + jl * 8) = ov;
  }
}

// ---------------------------------------------------------------------------
// Fallback (ws too small): fused gather + fp32 proj GEMM. Proven.
// ---------------------------------------------------------------------------
__global__ __launch_bounds__(256) void agg_proj_kernel(
    const unsigned short* __restrict__ v, const float* __restrict__ attn,
    const int* __restrict__ flows, const float* __restrict__ proj_w,
    const float* __restrict__ proj_b, float* __restrict__ out) {
  __shared__ float Agg[32][C];
  __shared__ float Bs[32][C];
  const int bid = blockIdx.x;
  const int t = bid >> 9;
  const int h0 = ((bid >> 5) & 15) * 8;
  const int w0 = (bid & 31) * 4;
  const int tid = threadIdx.x;

  const int g = tid >> 3;
  const int f4 = (tid & 7) * 4;
#pragma unroll
  for (int r = 0; r < 8; ++r) {
    const int pi = r * 32 + g;
    const int pos = pi >> 3;
    const int head = pi & 7;
    const int h = h0 + (pos >> 2);
    const int w = w0 + (pos & 3);
    const int base = (((head * T + t) * H + h) * W + w) * K;
    const int fbase = base * 3;
    float4 acc = {0.f, 0.f, 0.f, 0.f};
#pragma unroll
    for (int k = 0; k < K; ++k) {
      const int dt = flows[fbase + k * 3 + 0];
      const int dh = flows[fbase + k * 3 + 1];
      const int dw = flows[fbase + k * 3 + 2];
      const float aw = attn[base + k];
      const int tt = min(max(t + dt, 0), T - 1);
      const int hh = min(max(h + dh, 0), H - 1);
      const int ww = min(max(w + dw, 0), W - 1);
      const int mm = (tt * H + hh) * W + ww;
      const ushort4 r4 = *(const ushort4*)(v + (size_t)mm * C + head * F + f4);
      acc.x += aw * bf2f(r4.x);
      acc.y += aw * bf2f(r4.y);
      acc.z += aw * bf2f(r4.z);
      acc.w += aw * bf2f(r4.w);
    }
    *(float4*)&Agg[pos][head * F + f4] = acc;
  }
  __syncthreads();

  const int tx = tid & 31;
  const int ty = tid >> 5;
  float acc2[4][8];
  {
    const float4 b0 = *(const float4*)(proj_b + tx * 8);
    const float4 b1 = *(const float4*)(proj_b + tx * 8 + 4);
#pragma unroll
    for (int i = 0; i < 4; ++i) {
      acc2[i][0] = b0.x; acc2[i][1] = b0.y; acc2[i][2] = b0.z; acc2[i][3] = b0.w;
      acc2[i][4] = b1.x; acc2[i][5] = b1.y; acc2[i][6] = b1.z; acc2[i][7] = b1.w;
    }
  }
  for (int k0 = 0; k0 < C; k0 += 32) {
#pragma unroll
    for (int i = 0; i < 8; ++i) {
      const float4 w4 = *(const float4*)(proj_w + (size_t)tid * C + k0 + i * 4);
      Bs[i * 4 + 0][tid] = w4.x;
      Bs[i * 4 + 1][tid] = w4.y;
      Bs[i * 4 + 2][tid] = w4.z;
      Bs[i * 4 + 3][tid] = w4.w;
    }
    __syncthreads();
#pragma unroll 4
    for (int kk = 0; kk < 32; ++kk) {
      const float4 bb0 = *(const float4*)&Bs[kk][tx * 8];
      const float4 bb1 = *(const float4*)&Bs[kk][tx * 8 + 4];
      float a[4];
#pragma unroll
      for (int i = 0; i < 4; ++i) a[i] = Agg[ty * 4 + i][k0 + kk];
#pragma unroll
      for (int i = 0; i < 4; ++i) {
        acc2[i][0] += a[i] * bb0.x;
        acc2[i][1] += a[i] * bb0.y;
        acc2[i][2] += a[i] * bb0.z;
        acc2[i][3] += a[i] * bb0.w;
        acc2[i][4] += a[i] * bb1.x;
        acc2[i][5] += a[i] * bb1.y;
        acc2[i][6] += a[i] * bb1.z;
        acc2[i][7] += a[i] * bb1.w;
      }
    }
    __syncthreads();
  }
#pragma unroll
  for (int i = 0; i < 4; ++i) {
    const int pos = ty * 4 + i;
    const int h = h0 + (pos >> 2);
    const int w = w0 + (pos & 3);
    const int m = (t * H + h) * W + w;
    float4 o0, o1;
    o0.x = acc2[i][0]; o0.y = acc2[i][1]; o0.z = acc2[i][2]; o0.w = acc2[i][3];
    o1.x = acc2[i][4]; o1.y = acc2[i][5]; o1.z = acc2[i][6]; o1.w = acc2[i][7];
    *(float4*)(out + (size_t)m * C + tx * 8) = o0;
    *(float4*)(out + (size_t)m * C + tx * 8 + 4) = o1;
  }
}

}  // namespace

extern "C" void kernel_launch(void* const* d_in, const int* in_sizes, int n_in,
                              void* d_out, int out_size, void* d_ws,
                              size_t ws_size, hipStream_t stream) {
  const float* x = (const float*)d_in[0];
  const float* attn = (const float*)d_in[1];
  const int* flows = (const int*)d_in[2];
  const float* v_w = (const float*)d_in[3];
  const float* proj_w = (const float*)d_in[4];
  const float* proj_b = (const float*)d_in[5];
  float* out = (float*)d_out;

  const size_t VBYTES = (size_t)M * C * 2;  // 32 MB bf16
  unsigned short* v = (unsigned short*)d_ws;

  dim3 g1(M / 128, C / 128);
  mfma_gemm<0, false><<<g1, 256, 0, stream>>>(x, v_w, v, nullptr);

  if (ws_size >= 2 * VBYTES) {
    unsigned short* agg2 = (unsigned short*)((char*)d_ws + VBYTES);
    gather_lds_kernel<<<4096, 256, 0, stream>>>(v, attn, flows, agg2);
    mfma_gemm<2, true><<<g1, 256, 0, stream>>>(agg2, proj_w, out, proj_b);
  } else {
    const int nblk = T * (H / 8) * (W / 4);  // 2048
    agg_proj_kernel<<<nblk, 256, 0, stream>>>(v, attn, flows, proj_w, proj_b,
                                              out);
  }
}